// Round 13
// baseline (347.868 us; speedup 1.0000x reference)
//
#include <hip/hip_runtime.h>

#define NN 100000
#define NE 3200000
#define NQ (NE / 4)            // 800000 int4 quads

// ---- bucketed-scatter plan constants (R6/R12-proven geometry) ----
#define NCHUNK 32
#define CHUNK 3125             // 32 * 3125 = 100000 exactly; 12.5 KB LDS
#define NBB 512                // bucket blocks
#define BCAP 320               // per-(chunk,block) capacity: mean 195 + 9 sigma
#define NSLICE 16              // scatter slices
#define GPS (NBB / NSLICE)     // segments per scatter slice = 32
#define QPSEG (BCAP / 4)       // 80 uint4 quads per segment
#define BLK_QUADS (GPS * BCAP / 4)   // 2560 quads per scatter block

// MEASUREMENT ROUND: every phase repeats its (idempotent) body REP times so
// each dispatch is ~REP x its true cost -> visible in rocprof top-5.
#define REP 8

// --------------------------------------------------------------------------
__global__ __launch_bounds__(1024) void bucket_kernel(
        const int4* __restrict__ src4, const int4* __restrict__ dst4,
        unsigned* __restrict__ bkt, int* __restrict__ counts) {
    __shared__ int cnt[NCHUNK];
    const int b = blockIdx.x;
    const int q0 = (int)(((long long)b * NQ) / NBB);
    const int q1 = (int)(((long long)(b + 1) * NQ) / NBB);
    for (int rep = 0; rep < REP; ++rep) {
        if (threadIdx.x < NCHUNK) cnt[threadIdx.x] = 0;
        __syncthreads();
        for (int q = q0 + threadIdx.x; q < q1; q += 1024) {
            const int4 d = dst4[q];
            const int4 s = src4[q];
            const int dd[4] = {d.x, d.y, d.z, d.w};
            const int ss[4] = {s.x, s.y, s.z, s.w};
#pragma unroll
            for (int j = 0; j < 4; ++j) {
                const int c = dd[j] / CHUNK;              // magic-mul div
                const int slot = atomicAdd(&cnt[c], 1);
                bkt[((size_t)c * NBB + b) * BCAP + slot] =
                    ((unsigned)(dd[j] - c * CHUNK) << 17) | (unsigned)ss[j];
            }
        }
        __syncthreads();
    }
    if (threadIdx.x < NCHUNK)
        counts[threadIdx.x * NBB + b] = cnt[threadIdx.x];
}

// --------------------------------------------------------------------------
__global__ __launch_bounds__(1024) void scatter_bkt_kernel(
        const float* __restrict__ h,
        const unsigned* __restrict__ bkt, const int* __restrict__ counts,
        float* __restrict__ partial) {
    __shared__ float acc[CHUNK];
    __shared__ int cnt_l[GPS];
    const int s = blockIdx.x, c = blockIdx.y;
    if (threadIdx.x < GPS)
        cnt_l[threadIdx.x] = counts[c * NBB + s * GPS + threadIdx.x];
    const uint4* mp4 =
        (const uint4*)(bkt + ((size_t)c * NBB + s * GPS) * BCAP);
    for (int rep = 0; rep < REP; ++rep) {
        for (int i = threadIdx.x; i < CHUNK; i += 1024) acc[i] = 0.0f;
        __syncthreads();
        for (int quad = threadIdx.x; quad < BLK_QUADS; quad += 1024) {
            const uint4 e = mp4[quad];
            const int blk = quad / QPSEG;                 // magic-mul div
            const int idx = (quad - blk * QPSEG) * 4;
            const int n = cnt_l[blk];
            if (idx + 0 < n) atomicAdd(&acc[e.x >> 17], h[e.x & 0x1FFFF]);
            if (idx + 1 < n) atomicAdd(&acc[e.y >> 17], h[e.y & 0x1FFFF]);
            if (idx + 2 < n) atomicAdd(&acc[e.z >> 17], h[e.z & 0x1FFFF]);
            if (idx + 3 < n) atomicAdd(&acc[e.w >> 17], h[e.w & 0x1FFFF]);
        }
        __syncthreads();
    }
    float* outp = partial + ((size_t)c * NSLICE + s) * CHUNK;
    for (int i = threadIdx.x; i < CHUNK; i += 1024) outp[i] = acc[i];
}

// --------------------------------------------------------------------------
__global__ __launch_bounds__(256) void reduce_mlp_kernel(
        const float* __restrict__ partial,
        const float* __restrict__ W1, const float* __restrict__ b1,
        const float* __restrict__ W2,
        float* __restrict__ sout, int n) {
    int i = blockIdx.x * blockDim.x + threadIdx.x;
    if (i >= n) return;
    const int c = i / CHUNK;
    const int idx = i - c * CHUNK;
    const float* base = partial + (size_t)c * NSLICE * CHUNK + idx;
    float r = 0.0f;
    for (int rep = 0; rep < REP; ++rep) {
        float a = 0.0f;
#pragma unroll
        for (int s = 0; s < NSLICE; ++s) a += base[(size_t)s * CHUNK];
        r = 0.0f;
#pragma unroll
        for (int j = 0; j < 16; ++j)
            r = fmaf(fmaxf(fmaf(a, W1[j], b1[j]), 0.0f), W2[j], r);
    }
    sout[i] = r;
}

__global__ __launch_bounds__(256) void reduce_final_kernel(
        const float* __restrict__ partial,
        const float* __restrict__ b2,
        float* __restrict__ out, int n) {
    int i = blockIdx.x * blockDim.x + threadIdx.x;
    if (i >= n) return;
    const int c = i / CHUNK;
    const int idx = i - c * CHUNK;
    const float* base = partial + (size_t)c * NSLICE * CHUNK + idx;
    float v = 0.0f;
    for (int rep = 0; rep < REP; ++rep) {
        float a = 0.0f;
#pragma unroll
        for (int s = 0; s < NSLICE; ++s) a += base[(size_t)s * CHUNK];
        v = fmaxf(a + b2[0], 0.0f);
    }
    out[i] = v;
}

// ---------------- Fallback: global-atomic path ------------------------------
__global__ void zero_kernel(float* __restrict__ p, int n) {
    int i = blockIdx.x * blockDim.x + threadIdx.x;
    int st = gridDim.x * blockDim.x;
    for (; i < n; i += st) p[i] = 0.0f;
}
__global__ __launch_bounds__(256) void edge_scatter_kernel(
        const float* __restrict__ h, const int4* __restrict__ src4,
        const int4* __restrict__ dst4, float* __restrict__ agg, int nquad) {
    int i = blockIdx.x * blockDim.x + threadIdx.x;
    if (i >= nquad) return;
    int4 s = src4[i]; int4 d = dst4[i];
    atomicAdd(&agg[d.x], h[s.x]);
    atomicAdd(&agg[d.y], h[s.y]);
    atomicAdd(&agg[d.z], h[s.z]);
    atomicAdd(&agg[d.w], h[s.w]);
}
__global__ __launch_bounds__(256) void mlp_kernel(
        const float* __restrict__ agg1, const float* __restrict__ W1,
        const float* __restrict__ b1, const float* __restrict__ W2,
        float* __restrict__ sout, int n) {
    int i = blockIdx.x * blockDim.x + threadIdx.x;
    if (i >= n) return;
    float a = agg1[i], r = 0.0f;
#pragma unroll
    for (int j = 0; j < 16; ++j)
        r = fmaf(fmaxf(fmaf(a, W1[j], b1[j]), 0.0f), W2[j], r);
    sout[i] = r;
}
__global__ __launch_bounds__(256) void finalize_kernel(
        float* __restrict__ out, const float* __restrict__ b2, int n) {
    int i = blockIdx.x * blockDim.x + threadIdx.x;
    if (i >= n) return;
    out[i] = fmaxf(out[i] + b2[0], 0.0f);
}

extern "C" void kernel_launch(void* const* d_in, const int* in_sizes, int n_in,
                              void* d_out, int out_size, void* d_ws, size_t ws_size,
                              hipStream_t stream) {
    const float* features = (const float*)d_in[0];
    const int*   src      = (const int*)d_in[1];
    const int*   dst      = (const int*)d_in[2];
    const float* W1       = (const float*)d_in[3];
    const float* b1       = (const float*)d_in[4];
    const float* W2       = (const float*)d_in[5];
    const float* b2       = (const float*)d_in[6];
    float* out = (float*)d_out;

    const int4* src4 = (const int4*)src;
    const int4* dst4 = (const int4*)dst;
    const int nb = (NN + 255) / 256;

    // Plan A (instrumented, REP=8 inside each phase)
    {
        const size_t bkt_elems  = (size_t)NCHUNK * NBB * BCAP;       // 5.24M u32
        const size_t cnt_elems  = (size_t)NCHUNK * NBB;              // 16384 int
        const size_t part_elems = (size_t)NCHUNK * NSLICE * CHUNK;   // 1.6M f32
        const size_t need = (bkt_elems + cnt_elems + part_elems + NN) * 4;
        if (ws_size >= need) {
            unsigned* bkt  = (unsigned*)d_ws;
            int* counts    = (int*)(bkt + bkt_elems);
            float* partial = (float*)(counts + cnt_elems);
            float* sbuf    = partial + part_elems;

            bucket_kernel<<<NBB, 1024, 0, stream>>>(src4, dst4, bkt, counts);
            dim3 g(NSLICE, NCHUNK);
            scatter_bkt_kernel<<<g, 1024, 0, stream>>>(features, bkt, counts, partial);
            reduce_mlp_kernel<<<nb, 256, 0, stream>>>(partial, W1, b1, W2, sbuf, NN);
            scatter_bkt_kernel<<<g, 1024, 0, stream>>>(sbuf, bkt, counts, partial);
            reduce_final_kernel<<<nb, 256, 0, stream>>>(partial, b2, out, NN);
            return;
        }
    }
    // Fallback: global atomics
    {
        float* agg1 = (float*)d_ws;
        float* sbuf = agg1 + NN;
        const int eb = (NQ + 255) / 256;
        zero_kernel<<<256, 256, 0, stream>>>(agg1, NN);
        edge_scatter_kernel<<<eb, 256, 0, stream>>>(features, src4, dst4, agg1, NQ);
        mlp_kernel<<<nb, 256, 0, stream>>>(agg1, W1, b1, W2, sbuf, NN);
        zero_kernel<<<256, 256, 0, stream>>>(out, NN);
        edge_scatter_kernel<<<eb, 256, 0, stream>>>(sbuf, src4, dst4, out, NQ);
        finalize_kernel<<<nb, 256, 0, stream>>>(out, b2, NN);
    }
}

// Round 14
// 87.267 us; speedup vs baseline: 3.9862x; 3.9862x over previous
//
#include <hip/hip_runtime.h>

#define NN 100000
#define NE 3200000
#define NQ (NE / 4)            // 800000 int4 quads

// ---- bucketed-scatter plan constants (R6/R12-proven geometry) ----
#define NCHUNK 32
#define CHUNK 3125             // 32 * 3125 = 100000 exactly; 12.5 KB LDS
#define NBB 512                // bucket blocks
#define BCAP 320               // per-(chunk,block) capacity: mean 195 + 9 sigma
#define NSLICE 16              // scatter slices
#define GPS (NBB / NSLICE)     // segments per scatter slice = 32
#define QPSEG (BCAP / 4)       // 80 uint4 quads per segment
#define BLK_QUADS (GPS * BCAP / 4)   // 2560 quads per scatter block

// --------------------------------------------------------------------------
// Bucket (R6-exact): partition edges by dst-chunk into per-(chunk,block)
// segments via LDS atomic counters. Packed: dst_local(12b)<<17 | src(17b).
__global__ __launch_bounds__(1024) void bucket_kernel(
        const int4* __restrict__ src4, const int4* __restrict__ dst4,
        unsigned* __restrict__ bkt, int* __restrict__ counts) {
    __shared__ int cnt[NCHUNK];
    if (threadIdx.x < NCHUNK) cnt[threadIdx.x] = 0;
    __syncthreads();
    const int b = blockIdx.x;
    const int q0 = (int)(((long long)b * NQ) / NBB);
    const int q1 = (int)(((long long)(b + 1) * NQ) / NBB);
    for (int q = q0 + threadIdx.x; q < q1; q += 1024) {
        const int4 d = dst4[q];
        const int4 s = src4[q];
        const int dd[4] = {d.x, d.y, d.z, d.w};
        const int ss[4] = {s.x, s.y, s.z, s.w};
#pragma unroll
        for (int j = 0; j < 4; ++j) {
            const int c = dd[j] / CHUNK;                  // magic-mul div
            const int slot = atomicAdd(&cnt[c], 1);
            bkt[((size_t)c * NBB + b) * BCAP + slot] =
                ((unsigned)(dd[j] - c * CHUNK) << 17) | (unsigned)ss[j];
        }
    }
    __syncthreads();
    if (threadIdx.x < NCHUNK)
        counts[threadIdx.x * NBB + b] = cnt[threadIdx.x];
}

// --------------------------------------------------------------------------
// Scatter, deep-MLP form: each thread owns quads {tid, tid+1024, tid+2048}.
// ALL guarded h-gathers are hoisted before ANY LDS atomic so up to 12 misses
// stay in flight per thread (3x the previous 4). Nontemporal gathers skip
// the thrashing L1. Validity guards stay on loads (no OOB, no waste traffic).
__global__ __launch_bounds__(1024) void scatter_bkt_kernel(
        const float* __restrict__ h,
        const unsigned* __restrict__ bkt, const int* __restrict__ counts,
        float* __restrict__ partial) {
    __shared__ float acc[CHUNK];
    __shared__ int cnt_l[GPS];
    const int s = blockIdx.x, c = blockIdx.y;
    for (int i = threadIdx.x; i < CHUNK; i += 1024) acc[i] = 0.0f;
    if (threadIdx.x < GPS)
        cnt_l[threadIdx.x] = counts[c * NBB + s * GPS + threadIdx.x];
    __syncthreads();
    const uint4* mp4 =
        (const uint4*)(bkt + ((size_t)c * NBB + s * GPS) * BCAP);

    const int tid = threadIdx.x;
    const int qa = tid, qb = tid + 1024, qc = tid + 2048;
    const bool hasC = qc < BLK_QUADS;                     // tid < 512

    // meta loads (coalesced)
    const uint4 ea = mp4[qa];
    const uint4 eb = mp4[qb];
    uint4 ec = make_uint4(0u, 0u, 0u, 0u);
    if (hasC) ec = mp4[qc];

    // segment validity
    const int ba = qa / QPSEG, bb = qb / QPSEG, bc = qc / QPSEG;
    const int ia = (qa - ba * QPSEG) * 4;
    const int ib = (qb - bb * QPSEG) * 4;
    const int ic = (qc - bc * QPSEG) * 4;
    const int na = cnt_l[ba];
    const int nb = cnt_l[bb];
    const int nc = hasC ? cnt_l[bc] : 0;

    // hoisted guarded gathers — up to 12 in flight before first atomic
    float va0, va1, va2, va3, vb0, vb1, vb2, vb3, vc0, vc1, vc2, vc3;
    if (ia + 0 < na) va0 = __builtin_nontemporal_load(&h[ea.x & 0x1FFFF]);
    if (ia + 1 < na) va1 = __builtin_nontemporal_load(&h[ea.y & 0x1FFFF]);
    if (ia + 2 < na) va2 = __builtin_nontemporal_load(&h[ea.z & 0x1FFFF]);
    if (ia + 3 < na) va3 = __builtin_nontemporal_load(&h[ea.w & 0x1FFFF]);
    if (ib + 0 < nb) vb0 = __builtin_nontemporal_load(&h[eb.x & 0x1FFFF]);
    if (ib + 1 < nb) vb1 = __builtin_nontemporal_load(&h[eb.y & 0x1FFFF]);
    if (ib + 2 < nb) vb2 = __builtin_nontemporal_load(&h[eb.z & 0x1FFFF]);
    if (ib + 3 < nb) vb3 = __builtin_nontemporal_load(&h[eb.w & 0x1FFFF]);
    if (ic + 0 < nc) vc0 = __builtin_nontemporal_load(&h[ec.x & 0x1FFFF]);
    if (ic + 1 < nc) vc1 = __builtin_nontemporal_load(&h[ec.y & 0x1FFFF]);
    if (ic + 2 < nc) vc2 = __builtin_nontemporal_load(&h[ec.z & 0x1FFFF]);
    if (ic + 3 < nc) vc3 = __builtin_nontemporal_load(&h[ec.w & 0x1FFFF]);

    // LDS accumulate
    if (ia + 0 < na) atomicAdd(&acc[ea.x >> 17], va0);
    if (ia + 1 < na) atomicAdd(&acc[ea.y >> 17], va1);
    if (ia + 2 < na) atomicAdd(&acc[ea.z >> 17], va2);
    if (ia + 3 < na) atomicAdd(&acc[ea.w >> 17], va3);
    if (ib + 0 < nb) atomicAdd(&acc[eb.x >> 17], vb0);
    if (ib + 1 < nb) atomicAdd(&acc[eb.y >> 17], vb1);
    if (ib + 2 < nb) atomicAdd(&acc[eb.z >> 17], vb2);
    if (ib + 3 < nb) atomicAdd(&acc[eb.w >> 17], vb3);
    if (ic + 0 < nc) atomicAdd(&acc[ec.x >> 17], vc0);
    if (ic + 1 < nc) atomicAdd(&acc[ec.y >> 17], vc1);
    if (ic + 2 < nc) atomicAdd(&acc[ec.z >> 17], vc2);
    if (ic + 3 < nc) atomicAdd(&acc[ec.w >> 17], vc3);

    __syncthreads();
    float* outp = partial + ((size_t)c * NSLICE + s) * CHUNK;
    for (int i = threadIdx.x; i < CHUNK; i += 1024) outp[i] = acc[i];
}

// agg1 = sum over 16 slice partials; s = sum_j relu(agg1*W1+b1)*W2
__global__ __launch_bounds__(256) void reduce_mlp_kernel(
        const float* __restrict__ partial,
        const float* __restrict__ W1, const float* __restrict__ b1,
        const float* __restrict__ W2,
        float* __restrict__ sout, int n) {
    int i = blockIdx.x * blockDim.x + threadIdx.x;
    if (i >= n) return;
    const int c = i / CHUNK;
    const int idx = i - c * CHUNK;
    const float* base = partial + (size_t)c * NSLICE * CHUNK + idx;
    float a = 0.0f;
#pragma unroll
    for (int s = 0; s < NSLICE; ++s) a += base[(size_t)s * CHUNK];
    float r = 0.0f;
#pragma unroll
    for (int j = 0; j < 16; ++j)
        r = fmaf(fmaxf(fmaf(a, W1[j], b1[j]), 0.0f), W2[j], r);
    sout[i] = r;
}

__global__ __launch_bounds__(256) void reduce_final_kernel(
        const float* __restrict__ partial,
        const float* __restrict__ b2,
        float* __restrict__ out, int n) {
    int i = blockIdx.x * blockDim.x + threadIdx.x;
    if (i >= n) return;
    const int c = i / CHUNK;
    const int idx = i - c * CHUNK;
    const float* base = partial + (size_t)c * NSLICE * CHUNK + idx;
    float a = 0.0f;
#pragma unroll
    for (int s = 0; s < NSLICE; ++s) a += base[(size_t)s * CHUNK];
    out[i] = fmaxf(a + b2[0], 0.0f);
}

// ---------------- Fallback: global-atomic path ------------------------------
__global__ void zero_kernel(float* __restrict__ p, int n) {
    int i = blockIdx.x * blockDim.x + threadIdx.x;
    int st = gridDim.x * blockDim.x;
    for (; i < n; i += st) p[i] = 0.0f;
}
__global__ __launch_bounds__(256) void edge_scatter_kernel(
        const float* __restrict__ h, const int4* __restrict__ src4,
        const int4* __restrict__ dst4, float* __restrict__ agg, int nquad) {
    int i = blockIdx.x * blockDim.x + threadIdx.x;
    if (i >= nquad) return;
    int4 s = src4[i]; int4 d = dst4[i];
    atomicAdd(&agg[d.x], h[s.x]);
    atomicAdd(&agg[d.y], h[s.y]);
    atomicAdd(&agg[d.z], h[s.z]);
    atomicAdd(&agg[d.w], h[s.w]);
}
__global__ __launch_bounds__(256) void mlp_kernel(
        const float* __restrict__ agg1, const float* __restrict__ W1,
        const float* __restrict__ b1, const float* __restrict__ W2,
        float* __restrict__ sout, int n) {
    int i = blockIdx.x * blockDim.x + threadIdx.x;
    if (i >= n) return;
    float a = agg1[i], r = 0.0f;
#pragma unroll
    for (int j = 0; j < 16; ++j)
        r = fmaf(fmaxf(fmaf(a, W1[j], b1[j]), 0.0f), W2[j], r);
    sout[i] = r;
}
__global__ __launch_bounds__(256) void finalize_kernel(
        float* __restrict__ out, const float* __restrict__ b2, int n) {
    int i = blockIdx.x * blockDim.x + threadIdx.x;
    if (i >= n) return;
    out[i] = fmaxf(out[i] + b2[0], 0.0f);
}

extern "C" void kernel_launch(void* const* d_in, const int* in_sizes, int n_in,
                              void* d_out, int out_size, void* d_ws, size_t ws_size,
                              hipStream_t stream) {
    const float* features = (const float*)d_in[0];
    const int*   src      = (const int*)d_in[1];
    const int*   dst      = (const int*)d_in[2];
    const float* W1       = (const float*)d_in[3];
    const float* b1       = (const float*)d_in[4];
    const float* W2       = (const float*)d_in[5];
    const float* b2       = (const float*)d_in[6];
    float* out = (float*)d_out;

    const int4* src4 = (const int4*)src;
    const int4* dst4 = (const int4*)dst;
    const int nb = (NN + 255) / 256;

    // Plan A: bucketed scatter, deep-MLP scatter loop (~28 MB ws)
    {
        const size_t bkt_elems  = (size_t)NCHUNK * NBB * BCAP;       // 5.24M u32
        const size_t cnt_elems  = (size_t)NCHUNK * NBB;              // 16384 int
        const size_t part_elems = (size_t)NCHUNK * NSLICE * CHUNK;   // 1.6M f32
        const size_t need = (bkt_elems + cnt_elems + part_elems + NN) * 4;
        if (ws_size >= need) {
            unsigned* bkt  = (unsigned*)d_ws;
            int* counts    = (int*)(bkt + bkt_elems);
            float* partial = (float*)(counts + cnt_elems);
            float* sbuf    = partial + part_elems;

            bucket_kernel<<<NBB, 1024, 0, stream>>>(src4, dst4, bkt, counts);
            dim3 g(NSLICE, NCHUNK);
            scatter_bkt_kernel<<<g, 1024, 0, stream>>>(features, bkt, counts, partial);
            reduce_mlp_kernel<<<nb, 256, 0, stream>>>(partial, W1, b1, W2, sbuf, NN);
            scatter_bkt_kernel<<<g, 1024, 0, stream>>>(sbuf, bkt, counts, partial);
            reduce_final_kernel<<<nb, 256, 0, stream>>>(partial, b2, out, NN);
            return;
        }
    }
    // Fallback: global atomics
    {
        float* agg1 = (float*)d_ws;
        float* sbuf = agg1 + NN;
        const int eb = (NQ + 255) / 256;
        zero_kernel<<<256, 256, 0, stream>>>(agg1, NN);
        edge_scatter_kernel<<<eb, 256, 0, stream>>>(features, src4, dst4, agg1, NQ);
        mlp_kernel<<<nb, 256, 0, stream>>>(agg1, W1, b1, W2, sbuf, NN);
        zero_kernel<<<256, 256, 0, stream>>>(out, NN);
        edge_scatter_kernel<<<eb, 256, 0, stream>>>(sbuf, src4, dst4, out, NQ);
        finalize_kernel<<<nb, 256, 0, stream>>>(out, b2, NN);
    }
}

// Round 15
// 76.539 us; speedup vs baseline: 4.5450x; 1.1402x over previous
//
#include <hip/hip_runtime.h>

#define NN 100000
#define NE 3200000
#define NQ (NE / 4)            // 800000 int4 quads

// ---- bucketed-scatter plan constants (R6/R12-proven geometry) ----
#define NCHUNK 32
#define CHUNK 3125             // 32 * 3125 = 100000 exactly; 12.5 KB LDS
#define NBB 512                // bucket blocks
#define BCAP 320               // per-(chunk,block) capacity: mean 195 + 9 sigma
#define NSLICE 16              // scatter slices
#define GPS (NBB / NSLICE)     // segments per scatter slice = 32
#define QPSEG (BCAP / 4)       // 80 uint4 quads per segment
#define BLK_QUADS (GPS * BCAP / 4)   // 2560 quads per scatter block

// --------------------------------------------------------------------------
// Bucket (R6-exact): partition edges by dst-chunk into per-(chunk,block)
// segments via LDS atomic counters. Packed: dst_local(12b)<<17 | src(17b).
__global__ __launch_bounds__(1024) void bucket_kernel(
        const int4* __restrict__ src4, const int4* __restrict__ dst4,
        unsigned* __restrict__ bkt, int* __restrict__ counts) {
    __shared__ int cnt[NCHUNK];
    if (threadIdx.x < NCHUNK) cnt[threadIdx.x] = 0;
    __syncthreads();
    const int b = blockIdx.x;
    const int q0 = (int)(((long long)b * NQ) / NBB);
    const int q1 = (int)(((long long)(b + 1) * NQ) / NBB);
    for (int q = q0 + threadIdx.x; q < q1; q += 1024) {
        const int4 d = dst4[q];
        const int4 s = src4[q];
        const int dd[4] = {d.x, d.y, d.z, d.w};
        const int ss[4] = {s.x, s.y, s.z, s.w};
#pragma unroll
        for (int j = 0; j < 4; ++j) {
            const int c = dd[j] / CHUNK;                  // magic-mul div
            const int slot = atomicAdd(&cnt[c], 1);
            bkt[((size_t)c * NBB + b) * BCAP + slot] =
                ((unsigned)(dd[j] - c * CHUNK) << 17) | (unsigned)ss[j];
        }
    }
    __syncthreads();
    if (threadIdx.x < NCHUNK)
        counts[threadIdx.x * NBB + b] = cnt[threadIdx.x];
}

// --------------------------------------------------------------------------
// Scatter, hoisted-ILP form (R14 structure, PLAIN loads — the nt A/B):
// each thread owns quads {tid, tid+1024, tid+2048}; all guarded h-gathers
// issue before any LDS atomic -> up to 12 misses in flight per thread.
__global__ __launch_bounds__(1024) void scatter_bkt_kernel(
        const float* __restrict__ h,
        const unsigned* __restrict__ bkt, const int* __restrict__ counts,
        float* __restrict__ partial) {
    __shared__ float acc[CHUNK];
    __shared__ int cnt_l[GPS];
    const int s = blockIdx.x, c = blockIdx.y;
    for (int i = threadIdx.x; i < CHUNK; i += 1024) acc[i] = 0.0f;
    if (threadIdx.x < GPS)
        cnt_l[threadIdx.x] = counts[c * NBB + s * GPS + threadIdx.x];
    __syncthreads();
    const uint4* mp4 =
        (const uint4*)(bkt + ((size_t)c * NBB + s * GPS) * BCAP);

    const int tid = threadIdx.x;
    const int qa = tid, qb = tid + 1024, qc = tid + 2048;
    const bool hasC = qc < BLK_QUADS;                     // tid < 512

    // meta loads (coalesced)
    const uint4 ea = mp4[qa];
    const uint4 eb = mp4[qb];
    uint4 ec = make_uint4(0u, 0u, 0u, 0u);
    if (hasC) ec = mp4[qc];

    // segment validity
    const int ba = qa / QPSEG, bb = qb / QPSEG, bc = qc / QPSEG;
    const int ia = (qa - ba * QPSEG) * 4;
    const int ib = (qb - bb * QPSEG) * 4;
    const int ic = (qc - bc * QPSEG) * 4;
    const int na = cnt_l[ba];
    const int nb = cnt_l[bb];
    const int nc = hasC ? cnt_l[bc] : 0;

    // hoisted guarded gathers — up to 12 in flight before first atomic
    float va0 = 0.f, va1 = 0.f, va2 = 0.f, va3 = 0.f;
    float vb0 = 0.f, vb1 = 0.f, vb2 = 0.f, vb3 = 0.f;
    float vc0 = 0.f, vc1 = 0.f, vc2 = 0.f, vc3 = 0.f;
    if (ia + 0 < na) va0 = h[ea.x & 0x1FFFF];
    if (ia + 1 < na) va1 = h[ea.y & 0x1FFFF];
    if (ia + 2 < na) va2 = h[ea.z & 0x1FFFF];
    if (ia + 3 < na) va3 = h[ea.w & 0x1FFFF];
    if (ib + 0 < nb) vb0 = h[eb.x & 0x1FFFF];
    if (ib + 1 < nb) vb1 = h[eb.y & 0x1FFFF];
    if (ib + 2 < nb) vb2 = h[eb.z & 0x1FFFF];
    if (ib + 3 < nb) vb3 = h[eb.w & 0x1FFFF];
    if (ic + 0 < nc) vc0 = h[ec.x & 0x1FFFF];
    if (ic + 1 < nc) vc1 = h[ec.y & 0x1FFFF];
    if (ic + 2 < nc) vc2 = h[ec.z & 0x1FFFF];
    if (ic + 3 < nc) vc3 = h[ec.w & 0x1FFFF];

    // LDS accumulate
    if (ia + 0 < na) atomicAdd(&acc[ea.x >> 17], va0);
    if (ia + 1 < na) atomicAdd(&acc[ea.y >> 17], va1);
    if (ia + 2 < na) atomicAdd(&acc[ea.z >> 17], va2);
    if (ia + 3 < na) atomicAdd(&acc[ea.w >> 17], va3);
    if (ib + 0 < nb) atomicAdd(&acc[eb.x >> 17], vb0);
    if (ib + 1 < nb) atomicAdd(&acc[eb.y >> 17], vb1);
    if (ib + 2 < nb) atomicAdd(&acc[eb.z >> 17], vb2);
    if (ib + 3 < nb) atomicAdd(&acc[eb.w >> 17], vb3);
    if (ic + 0 < nc) atomicAdd(&acc[ec.x >> 17], vc0);
    if (ic + 1 < nc) atomicAdd(&acc[ec.y >> 17], vc1);
    if (ic + 2 < nc) atomicAdd(&acc[ec.z >> 17], vc2);
    if (ic + 3 < nc) atomicAdd(&acc[ec.w >> 17], vc3);

    __syncthreads();
    float* outp = partial + ((size_t)c * NSLICE + s) * CHUNK;
    for (int i = threadIdx.x; i < CHUNK; i += 1024) outp[i] = acc[i];
}

// agg1 = sum over 16 slice partials; s = sum_j relu(agg1*W1+b1)*W2
__global__ __launch_bounds__(256) void reduce_mlp_kernel(
        const float* __restrict__ partial,
        const float* __restrict__ W1, const float* __restrict__ b1,
        const float* __restrict__ W2,
        float* __restrict__ sout, int n) {
    int i = blockIdx.x * blockDim.x + threadIdx.x;
    if (i >= n) return;
    const int c = i / CHUNK;
    const int idx = i - c * CHUNK;
    const float* base = partial + (size_t)c * NSLICE * CHUNK + idx;
    float a = 0.0f;
#pragma unroll
    for (int s = 0; s < NSLICE; ++s) a += base[(size_t)s * CHUNK];
    float r = 0.0f;
#pragma unroll
    for (int j = 0; j < 16; ++j)
        r = fmaf(fmaxf(fmaf(a, W1[j], b1[j]), 0.0f), W2[j], r);
    sout[i] = r;
}

__global__ __launch_bounds__(256) void reduce_final_kernel(
        const float* __restrict__ partial,
        const float* __restrict__ b2,
        float* __restrict__ out, int n) {
    int i = blockIdx.x * blockDim.x + threadIdx.x;
    if (i >= n) return;
    const int c = i / CHUNK;
    const int idx = i - c * CHUNK;
    const float* base = partial + (size_t)c * NSLICE * CHUNK + idx;
    float a = 0.0f;
#pragma unroll
    for (int s = 0; s < NSLICE; ++s) a += base[(size_t)s * CHUNK];
    out[i] = fmaxf(a + b2[0], 0.0f);
}

// ---------------- Fallback: global-atomic path ------------------------------
__global__ void zero_kernel(float* __restrict__ p, int n) {
    int i = blockIdx.x * blockDim.x + threadIdx.x;
    int st = gridDim.x * blockDim.x;
    for (; i < n; i += st) p[i] = 0.0f;
}
__global__ __launch_bounds__(256) void edge_scatter_kernel(
        const float* __restrict__ h, const int4* __restrict__ src4,
        const int4* __restrict__ dst4, float* __restrict__ agg, int nquad) {
    int i = blockIdx.x * blockDim.x + threadIdx.x;
    if (i >= nquad) return;
    int4 s = src4[i]; int4 d = dst4[i];
    atomicAdd(&agg[d.x], h[s.x]);
    atomicAdd(&agg[d.y], h[s.y]);
    atomicAdd(&agg[d.z], h[s.z]);
    atomicAdd(&agg[d.w], h[s.w]);
}
__global__ __launch_bounds__(256) void mlp_kernel(
        const float* __restrict__ agg1, const float* __restrict__ W1,
        const float* __restrict__ b1, const float* __restrict__ W2,
        float* __restrict__ sout, int n) {
    int i = blockIdx.x * blockDim.x + threadIdx.x;
    if (i >= n) return;
    float a = agg1[i], r = 0.0f;
#pragma unroll
    for (int j = 0; j < 16; ++j)
        r = fmaf(fmaxf(fmaf(a, W1[j], b1[j]), 0.0f), W2[j], r);
    sout[i] = r;
}
__global__ __launch_bounds__(256) void finalize_kernel(
        float* __restrict__ out, const float* __restrict__ b2, int n) {
    int i = blockIdx.x * blockDim.x + threadIdx.x;
    if (i >= n) return;
    out[i] = fmaxf(out[i] + b2[0], 0.0f);
}

extern "C" void kernel_launch(void* const* d_in, const int* in_sizes, int n_in,
                              void* d_out, int out_size, void* d_ws, size_t ws_size,
                              hipStream_t stream) {
    const float* features = (const float*)d_in[0];
    const int*   src      = (const int*)d_in[1];
    const int*   dst      = (const int*)d_in[2];
    const float* W1       = (const float*)d_in[3];
    const float* b1       = (const float*)d_in[4];
    const float* W2       = (const float*)d_in[5];
    const float* b2       = (const float*)d_in[6];
    float* out = (float*)d_out;

    const int4* src4 = (const int4*)src;
    const int4* dst4 = (const int4*)dst;
    const int nb = (NN + 255) / 256;

    // Plan A: bucketed scatter, hoisted-ILP scatter with plain loads (~28 MB ws)
    {
        const size_t bkt_elems  = (size_t)NCHUNK * NBB * BCAP;       // 5.24M u32
        const size_t cnt_elems  = (size_t)NCHUNK * NBB;              // 16384 int
        const size_t part_elems = (size_t)NCHUNK * NSLICE * CHUNK;   // 1.6M f32
        const size_t need = (bkt_elems + cnt_elems + part_elems + NN) * 4;
        if (ws_size >= need) {
            unsigned* bkt  = (unsigned*)d_ws;
            int* counts    = (int*)(bkt + bkt_elems);
            float* partial = (float*)(counts + cnt_elems);
            float* sbuf    = partial + part_elems;

            bucket_kernel<<<NBB, 1024, 0, stream>>>(src4, dst4, bkt, counts);
            dim3 g(NSLICE, NCHUNK);
            scatter_bkt_kernel<<<g, 1024, 0, stream>>>(features, bkt, counts, partial);
            reduce_mlp_kernel<<<nb, 256, 0, stream>>>(partial, W1, b1, W2, sbuf, NN);
            scatter_bkt_kernel<<<g, 1024, 0, stream>>>(sbuf, bkt, counts, partial);
            reduce_final_kernel<<<nb, 256, 0, stream>>>(partial, b2, out, NN);
            return;
        }
    }
    // Fallback: global atomics
    {
        float* agg1 = (float*)d_ws;
        float* sbuf = agg1 + NN;
        const int eb = (NQ + 255) / 256;
        zero_kernel<<<256, 256, 0, stream>>>(agg1, NN);
        edge_scatter_kernel<<<eb, 256, 0, stream>>>(features, src4, dst4, agg1, NQ);
        mlp_kernel<<<nb, 256, 0, stream>>>(agg1, W1, b1, W2, sbuf, NN);
        zero_kernel<<<256, 256, 0, stream>>>(out, NN);
        edge_scatter_kernel<<<eb, 256, 0, stream>>>(sbuf, src4, dst4, out, NQ);
        finalize_kernel<<<nb, 256, 0, stream>>>(out, b2, NN);
    }
}